// Round 1
// baseline (92.971 us; speedup 1.0000x reference)
//
#include <hip/hip_runtime.h>

// Conv2dfft == direct 3x3 cross-correlation, pad=1, + bias (FFT grid never wraps).
// x: [32,128,32,32] f32; w: [128,128,3,3] f32; b: [128] f32; out: [32,128,32,32] f32.
// Strategy: pack to bf16 (NHWC padded / tap-major weights), implicit-GEMM with
// mfma_f32_16x16x32_bf16, global_load_lds(16B) staging.

typedef __attribute__((ext_vector_type(8))) short bf16x8;
typedef __attribute__((ext_vector_type(4))) float f32x4;

#define N_IMG 32
#define C_IN  128
#define F_OUT 128
#define HW    32
#define HPAD  34

__device__ __forceinline__ unsigned short f2bf(float f) {
    union { float f; unsigned u; } v; v.f = f;
    unsigned r = v.u + 0x7fffu + ((v.u >> 16) & 1u);   // RNE
    return (unsigned short)(r >> 16);
}

// ---------------- pack x: [N,C,32,32] f32 -> [N,34,34,C] bf16, zero border ----
__global__ __launch_bounds__(256) void pack_x_kernel(const float* __restrict__ x,
                                                     unsigned short* __restrict__ xp) {
    __shared__ unsigned short tile[C_IN * HPAD];   // [c][wp]  (stride 34: conflict-light)
    const int n   = blockIdx.x / HPAD;
    const int hp  = blockIdx.x - n * HPAD;
    const int tid = threadIdx.x;
    const unsigned base_out = (unsigned)(n * HPAD + hp) * (HPAD * C_IN);
    if (hp >= 1 && hp <= 32) {
        const int h = hp - 1;
        #pragma unroll
        for (int i = 0; i < 16; ++i) {                 // 4096 = 128c * 32w, coalesced reads
            int idx = tid + i * 256;
            int c = idx >> 5, w = idx & 31;
            tile[c * HPAD + (w + 1)] = f2bf(x[((n * C_IN + c) * HW + h) * HW + w]);
        }
        if (tid < C_IN) { tile[tid * HPAD] = 0; tile[tid * HPAD + 33] = 0; }
        __syncthreads();
        #pragma unroll
        for (int i = 0; i < 17; ++i) {                 // 4352 = 34wp * 128c, coalesced writes
            int idx = tid + i * 256;
            int wp = idx >> 7, c = idx & 127;
            xp[base_out + (unsigned)idx] = tile[c * HPAD + wp];
        }
    } else {
        #pragma unroll
        for (int i = 0; i < 17; ++i) {
            int idx = tid + i * 256;
            xp[base_out + (unsigned)idx] = 0;
        }
    }
}

// ---------------- pack w: [F,C,3,3] f32 -> [tap 9][cchunk 4][f 128][ci 32] bf16 -
__global__ __launch_bounds__(256) void pack_w_kernel(const float* __restrict__ w,
                                                     unsigned short* __restrict__ wpk) {
    int idx = blockIdx.x * 256 + threadIdx.x;          // < 147456 = 9*4*128*32
    int ci = idx & 31;
    int f  = (idx >> 5) & 127;
    int cc = (idx >> 12) & 3;
    int t  = idx >> 14;                                // t = r*3+s
    int c  = cc * 32 + ci;
    wpk[idx] = f2bf(w[(f * C_IN + c) * 9 + t]);
}

// ---------------- implicit-GEMM conv ----------------------------------------
// grid 256: blockIdx -> (f-half, image n, 8-row band h0). Block = 64f x 256pos.
// 4 waves along positions; wave = 64f x 64pos = 4x4 tiles of 16x16x32 MFMA.
__global__ __launch_bounds__(256, 1) void conv_gemm_kernel(
    const unsigned short* __restrict__ xp,
    const unsigned short* __restrict__ wpk,
    const float* __restrict__ bias,
    float* __restrict__ out)
{
    __shared__ alignas(16) unsigned short lds_x[10 * HPAD * 32]; // 10880 el = 21760 B
    __shared__ alignas(16) unsigned short lds_a[5 * 64 * 32];    // 10240 el = 20480 B

    const int tid  = threadIdx.x;
    const int lane = tid & 63;
    const int wave = tid >> 6;
    const int qk   = lane >> 4;      // k-group 0..3
    const int l15  = lane & 15;

    const int f0 = (blockIdx.x & 1) * 64;
    const int pb = blockIdx.x >> 1;
    const int n  = pb >> 2;
    const int h0 = (pb & 3) * 8;

    f32x4 acc[4][4];
    #pragma unroll
    for (int mi = 0; mi < 4; ++mi)
        #pragma unroll
        for (int ni = 0; ni < 4; ++ni)
            acc[mi][ni] = (f32x4){0.f, 0.f, 0.f, 0.f};

    // B-fragment LDS element base per ni (tap adds (r*34+s)*32)
    int b_base[4];
    #pragma unroll
    for (int ni = 0; ni < 4; ++ni) {
        int p = wave * 64 + ni * 16 + l15;             // 0..255
        b_base[ni] = ((p >> 5) * HPAD + (p & 31)) * 32 + qk * 8;
    }
    const int a_off = l15 * 32 + qk * 8;

    const unsigned short* xsrc0 = xp + (unsigned)((n * HPAD + h0) * HPAD) * C_IN;

    for (int cc = 0; cc < 4; ++cc) {
        __syncthreads();   // previous iteration's LDS reads done
        // ---- stage X tile: rows h0..h0+9, wv 0..33, c chunk cc  (1360 x 16B)
        #pragma unroll
        for (int i = 0; i < 6; ++i) {
            int idx = tid + i * 256;
            if (idx < 1360) {
                unsigned g = (unsigned)idx >> 2;       // (dh,wv) run, 4 chunks each
                int dh = (int)(g / 34u);
                int wv = (int)(g - (unsigned)dh * 34u);
                int ci0 = (idx & 3) * 8;
                const unsigned short* src = xsrc0 + (dh * HPAD + wv) * C_IN + cc * 32 + ci0;
                __builtin_amdgcn_global_load_lds(
                    (const __attribute__((address_space(1))) void*)src,
                    (__attribute__((address_space(3))) void*)(&lds_x[idx * 8]),
                    16, 0, 0);
            }
        }
        #pragma unroll
        for (int half = 0; half < 2; ++half) {
            const int t0 = half ? 5 : 0;
            const int ntaps = half ? 4 : 5;
            if (half) __syncthreads();                 // lds_a reads of prev half done
            // ---- stage A tiles for taps t0..t0+ntaps-1, chunk cc
            #pragma unroll
            for (int i = 0; i < 5; ++i) {
                int idx = tid + i * 256;
                if (idx < ntaps * 256) {
                    int tl = idx >> 8;
                    int rem = idx & 255;
                    const unsigned short* src =
                        wpk + (unsigned)((((t0 + tl) * 4 + cc) * 128) + f0 + (rem >> 2)) * 32
                            + (rem & 3) * 8;
                    __builtin_amdgcn_global_load_lds(
                        (const __attribute__((address_space(1))) void*)src,
                        (__attribute__((address_space(3))) void*)(&lds_a[idx * 8]),
                        16, 0, 0);
                }
            }
            __syncthreads();   // drains vmcnt (compiler emits waitcnt before barrier)
            // ---- compute
            #pragma unroll
            for (int tl = 0; tl < 5; ++tl) {
                if (tl < ntaps) {
                    const int t = t0 + tl;
                    const int r = t / 3, s = t - r * 3;
                    const int tap_off = (r * HPAD + s) * 32;
                    bf16x8 af[4], bfr[4];
                    #pragma unroll
                    for (int mi = 0; mi < 4; ++mi)
                        af[mi] = *(const bf16x8*)&lds_a[tl * 2048 + mi * 512 + a_off];
                    #pragma unroll
                    for (int ni = 0; ni < 4; ++ni)
                        bfr[ni] = *(const bf16x8*)&lds_x[b_base[ni] + tap_off];
                    #pragma unroll
                    for (int mi = 0; mi < 4; ++mi)
                        #pragma unroll
                        for (int ni = 0; ni < 4; ++ni)
                            acc[mi][ni] = __builtin_amdgcn_mfma_f32_16x16x32_bf16(
                                af[mi], bfr[ni], acc[mi][ni], 0, 0, 0);
                }
            }
        }
    }

    // ---- epilogue: D row = qk*4 + reg (f dim), col = l15 (position dim)
    #pragma unroll
    for (int mi = 0; mi < 4; ++mi) {
        const int f_base = f0 + mi * 16 + qk * 4;
        float bv[4];
        #pragma unroll
        for (int r = 0; r < 4; ++r) bv[r] = bias[f_base + r];
        #pragma unroll
        for (int ni = 0; ni < 4; ++ni) {
            int p = wave * 64 + ni * 16 + l15;
            int h = h0 + (p >> 5), w2 = p & 31;
            #pragma unroll
            for (int r = 0; r < 4; ++r) {
                out[((unsigned)(n * F_OUT + f_base + r) * HW + h) * HW + w2] =
                    acc[mi][ni][r] + bv[r];
            }
        }
    }
}

extern "C" void kernel_launch(void* const* d_in, const int* in_sizes, int n_in,
                              void* d_out, int out_size, void* d_ws, size_t ws_size,
                              hipStream_t stream) {
    const float* x = (const float*)d_in[0];
    const float* w = (const float*)d_in[1];
    const float* b = (const float*)d_in[2];
    float* out = (float*)d_out;

    unsigned short* xp  = (unsigned short*)d_ws;                 // 32*34*34*128 bf16
    unsigned short* wpk = xp + (size_t)N_IMG * HPAD * HPAD * C_IN; // 9*4*128*32 bf16

    pack_x_kernel<<<N_IMG * HPAD, 256, 0, stream>>>(x, xp);
    pack_w_kernel<<<576, 256, 0, stream>>>(w, wpk);
    conv_gemm_kernel<<<256, 256, 0, stream>>>(xp, wpk, b, out);
}

// Round 2
// 90.642 us; speedup vs baseline: 1.0257x; 1.0257x over previous
//
#include <hip/hip_runtime.h>

// Conv2dfft == direct 3x3 cross-correlation, pad=1, + bias (FFT grid never wraps).
// x: [32,128,32,32] f32; w: [128,128,3,3] f32; b: [128] f32; out: [32,128,32,32] f32.
// R2: implicit-GEMM, grid 512 (2 blocks/CU), 4 barrier phases (one per 32-ch K chunk),
// XOR-swizzled LDS (kills the 8-way ds_read_b128 conflicts), wave-aligned staging.

typedef __attribute__((ext_vector_type(8))) short bf16x8;
typedef __attribute__((ext_vector_type(4))) float f32x4;

#define N_IMG 32
#define C_IN  128
#define F_OUT 128
#define HW    32
#define HPAD  34

__device__ __forceinline__ unsigned short f2bf(float f) {
    union { float f; unsigned u; } v; v.f = f;
    unsigned r = v.u + 0x7fffu + ((v.u >> 16) & 1u);   // RNE
    return (unsigned short)(r >> 16);
}

// ---------------- pack x: [N,C,32,32] f32 -> [N,34,34,C] bf16, zero border ----
__global__ __launch_bounds__(256) void pack_x_kernel(const float* __restrict__ x,
                                                     unsigned short* __restrict__ xp) {
    __shared__ unsigned short tile[C_IN * HPAD];   // [c][wp]
    const int n   = blockIdx.x / HPAD;
    const int hp  = blockIdx.x - n * HPAD;
    const int tid = threadIdx.x;
    const unsigned base_out = (unsigned)(n * HPAD + hp) * (HPAD * C_IN);
    if (hp >= 1 && hp <= 32) {
        const int h = hp - 1;
        #pragma unroll
        for (int i = 0; i < 16; ++i) {                 // 4096 = 128c * 32w, coalesced reads
            int idx = tid + i * 256;
            int c = idx >> 5, w = idx & 31;
            tile[c * HPAD + (w + 1)] = f2bf(x[((n * C_IN + c) * HW + h) * HW + w]);
        }
        if (tid < C_IN) { tile[tid * HPAD] = 0; tile[tid * HPAD + 33] = 0; }
        __syncthreads();
        #pragma unroll
        for (int i = 0; i < 17; ++i) {                 // 4352 = 34wp * 128c, coalesced writes
            int idx = tid + i * 256;
            int wp = idx >> 7, c = idx & 127;
            xp[base_out + (unsigned)idx] = tile[c * HPAD + wp];
        }
    } else {
        #pragma unroll
        for (int i = 0; i < 17; ++i) {
            int idx = tid + i * 256;
            xp[base_out + (unsigned)idx] = 0;
        }
    }
}

// ------- pack w: [F,C,3,3] f32 -> [cc 4][tap 9][f 128][ci 32] bf16 (cc outermost)
__global__ __launch_bounds__(256) void pack_w_kernel(const float* __restrict__ w,
                                                     unsigned short* __restrict__ wpk) {
    int idx = blockIdx.x * 256 + threadIdx.x;          // < 147456
    int ci = idx & 31;
    int f  = (idx >> 5) & 127;
    int u  = idx >> 12;                                // 0..35 = cc*9 + t
    int cc = u / 9;
    int t  = u - cc * 9;
    wpk[idx] = f2bf(w[(f * C_IN + cc * 32 + ci) * 9 + t]);
}

// ---------------- implicit-GEMM conv ----------------------------------------
// grid 512: (n 32) x (band 8: 4 output rows) x (f-half 2). Block 256 = 4 waves.
// Block tile 64f x 128pos; wave tile 64f x 32pos (one output row), acc[4][2].
// K = 1152 as 4 chunks of (9 taps x 32c); one stage+barrier pair per chunk.
// LDS 16B-chunk XOR swizzle: physical chunk = logical ^ ((row>>1)&3).
__global__ __launch_bounds__(256, 2) void conv_gemm_kernel(
    const unsigned short* __restrict__ xp,
    const unsigned short* __restrict__ wpk,
    const float* __restrict__ bias,
    float* __restrict__ out)
{
    __shared__ alignas(16) unsigned short lds_x[1024 * 8];   // rows 0..203 real, rest dump pad
    __shared__ alignas(16) unsigned short lds_a[2304 * 8];   // [tap 9][fl 64] rows x 4 chunks

    const int tid  = threadIdx.x;
    const int lane = tid & 63;
    const int wave = tid >> 6;
    const int qk   = lane >> 4;      // k-group 0..3 (logical 16B chunk)
    const int l15  = lane & 15;

    const int fh   = blockIdx.x & 1;
    const int band = (blockIdx.x >> 1) & 7;
    const int n    = blockIdx.x >> 4;
    const int f0   = fh * 64;
    const int h0   = band * 4;

    f32x4 acc[4][2];
    #pragma unroll
    for (int mi = 0; mi < 4; ++mi)
        #pragma unroll
        for (int ni = 0; ni < 2; ++ni)
            acc[mi][ni] = (f32x4){0.f, 0.f, 0.f, 0.f};

    // compute-side fragment bases (element offsets into LDS, pre-swizzled where static)
    const int a_lane = l15 * 32 + (((qk ^ (l15 >> 1)) & 3) << 3);
    int brow0[2];
    #pragma unroll
    for (int ni = 0; ni < 2; ++ni)
        brow0[ni] = wave * HPAD + ni * 16 + l15;     // + r*34+s at use site

    const unsigned short* xsrc0 = xp + (unsigned)((n * HPAD + h0) * HPAD) * C_IN;
    const unsigned short* wbase = wpk + f0 * 32;

    for (int cc = 0; cc < 4; ++cc) {
        __syncthreads();   // previous chunk's LDS reads complete before overwrite
        // ---- stage x: 1024 slots (816 real), rows (dh,wv) = dh*34+wv, 4 x 16B per row
        #pragma unroll
        for (int i = 0; i < 4; ++i) {
            int p = tid + i * 256;
            int row = p >> 2;  if (row > 203) row = 203;      // dump slots clamp src
            int lc = (p ^ (row >> 1)) & 3;                    // logical chunk for phys p&3
            const unsigned short* src = xsrc0 + row * C_IN + cc * 32 + lc * 8;
            __builtin_amdgcn_global_load_lds(
                (const __attribute__((address_space(1))) void*)src,
                (__attribute__((address_space(3))) void*)(&lds_x[p * 8]),
                16, 0, 0);
        }
        // ---- stage a: 2304 slots = (tap*64+fl) rows x 4 chunks
        const unsigned short* wsrc = wbase + cc * 36864;      // (cc*9 taps)*128f*32c
        #pragma unroll
        for (int j = 0; j < 9; ++j) {
            int q = tid + j * 256;
            int row = q >> 2;                                 // tap*64 + fl
            int lc = (q ^ (row >> 1)) & 3;
            const unsigned short* src = wsrc + ((row >> 6) * 4096) + ((row & 63) * 32) + lc * 8;
            __builtin_amdgcn_global_load_lds(
                (const __attribute__((address_space(1))) void*)src,
                (__attribute__((address_space(3))) void*)(&lds_a[q * 8]),
                16, 0, 0);
        }
        __syncthreads();   // drain vmcnt
        // ---- compute: 9 taps x (4mi x 2ni) MFMAs
        #pragma unroll
        for (int tap = 0; tap < 9; ++tap) {
            const int r = tap / 3, s = tap - 3 * (tap / 3);
            bf16x8 af[4], bf[2];
            #pragma unroll
            for (int mi = 0; mi < 4; ++mi)
                af[mi] = *(const bf16x8*)&lds_a[tap * 2048 + mi * 512 + a_lane];
            #pragma unroll
            for (int ni = 0; ni < 2; ++ni) {
                int row = brow0[ni] + (r * HPAD + s);
                int el  = (row << 5) + (((qk ^ (row >> 1)) & 3) << 3);
                bf[ni] = *(const bf16x8*)&lds_x[el];
            }
            #pragma unroll
            for (int mi = 0; mi < 4; ++mi)
                #pragma unroll
                for (int ni = 0; ni < 2; ++ni)
                    acc[mi][ni] = __builtin_amdgcn_mfma_f32_16x16x32_bf16(
                        af[mi], bf[ni], acc[mi][ni], 0, 0, 0);
        }
    }

    // ---- epilogue: D row (f) = qk*4 + reg, col (pos) = l15; wave owns out row h0+wave
    const int h = h0 + wave;
    #pragma unroll
    for (int mi = 0; mi < 4; ++mi) {
        const int f_base = f0 + mi * 16 + qk * 4;
        float bv[4];
        #pragma unroll
        for (int r2 = 0; r2 < 4; ++r2) bv[r2] = bias[f_base + r2];
        #pragma unroll
        for (int ni = 0; ni < 2; ++ni) {
            const int w2 = ni * 16 + l15;
            #pragma unroll
            for (int r2 = 0; r2 < 4; ++r2) {
                out[((unsigned)(n * F_OUT + f_base + r2) * HW + h) * HW + w2] =
                    acc[mi][ni][r2] + bv[r2];
            }
        }
    }
}

extern "C" void kernel_launch(void* const* d_in, const int* in_sizes, int n_in,
                              void* d_out, int out_size, void* d_ws, size_t ws_size,
                              hipStream_t stream) {
    const float* x = (const float*)d_in[0];
    const float* w = (const float*)d_in[1];
    const float* b = (const float*)d_in[2];
    float* out = (float*)d_out;

    unsigned short* xp  = (unsigned short*)d_ws;                   // 32*34*34*128 bf16
    unsigned short* wpk = xp + (size_t)N_IMG * HPAD * HPAD * C_IN; // 4*9*128*32 bf16

    pack_x_kernel<<<N_IMG * HPAD, 256, 0, stream>>>(x, xp);
    pack_w_kernel<<<576, 256, 0, stream>>>(w, wpk);
    conv_gemm_kernel<<<512, 256, 0, stream>>>(xp, wpk, b, out);
}